// Round 10
// baseline (175.157 us; speedup 1.0000x reference)
//
#include <hip/hip_runtime.h>
#include <math.h>

#define D 8
// ---- coarse-sort fast path ----
#define NPC 512            // nodes per coarse bucket (power of 2)
#define NPCSH 9
#define NCMAX 512          // max coarse buckets on fast path
#define EPB 3072           // edges per phase-A block (payload lives in LDS)
#define APT 1024           // phase-A threads
#define BCH 1536           // phase-B chunk (records)
#define BPT 1024           // phase-B threads
// ---- pairs fallback path ----
#define BSH 6
#define BMASK 63
#define NBMAX 1600
#define EPBF 6250          // fallback pairs-path edges per block
#define RPT5 512

// ---- bf16 helpers ----
__device__ __forceinline__ unsigned pk_bf16(float a, float b) {
    unsigned ua = __float_as_uint(a), ub = __float_as_uint(b);
    ua = (ua + 0x7FFFu + ((ua >> 16) & 1u)) >> 16;   // RTNE
    ub = (ub + 0x7FFFu + ((ub >> 16) & 1u)) >> 16;
    return ua | (ub << 16);
}
__device__ __forceinline__ float bf_lo(unsigned u) { return __uint_as_float(u << 16); }
__device__ __forceinline__ float bf_hi(unsigned u) { return __uint_as_float(u & 0xFFFF0000u); }

__global__ void zero_cursors_kernel(unsigned* __restrict__ cur, int n) {
    int i = blockIdx.x * blockDim.x + threadIdx.x;
    if (i < n) cur[i] = 0u;
}

// block-wide exclusive scan over NB bins (NB multiple of 64, <= blockDim)
template<int NB>
__device__ __forceinline__ void scan_bins(unsigned* hist, unsigned* incl,
                                          unsigned* starts, unsigned* cur,
                                          unsigned* wsum, unsigned* woff) {
    int tid = threadIdx.x;
    if (tid < NB) {
        int l = tid & 63;
        unsigned v = hist[tid], s = v;
#pragma unroll
        for (int dd = 1; dd < 64; dd <<= 1) {
            unsigned tt = __shfl_up(s, dd, 64);
            if (l >= dd) s += tt;
        }
        incl[tid] = s;
        if (l == 63) wsum[tid >> 6] = s;
    }
    __syncthreads();
    if (tid == 0) {
        unsigned o = 0;
#pragma unroll
        for (int w = 0; w < NB / 64; ++w) { woff[w] = o; o += wsum[w]; }
    }
    __syncthreads();
    if (tid < NB) {
        unsigned st = incl[tid] - hist[tid] + woff[tid >> 6];
        starts[tid] = st;
        cur[tid] = st;
    }
    __syncthreads();
}

// =============== coarse-sort path: phase A (payload in LDS, ILP-unrolled) ===============

__global__ __launch_bounds__(APT, 8) void edge_sort3_kernel(
    const float4* __restrict__ x4,
    const int* __restrict__ src_idx,
    const int* __restrict__ dst_idx,
    const float4* __restrict__ ea4,
    float4* __restrict__ out_edge4,
    unsigned* __restrict__ gcur,          // [nc]
    uint4* __restrict__ vals,             // [nc*cap]
    unsigned short* __restrict__ locs,    // [nc*cap]
    int n_edges, int nc, int cap)
{
    __shared__ uint4 pay[EPB];            // 49152 B — bf16 payload
    __shared__ unsigned key[EPB];         // 12288 B — dst node id
    __shared__ unsigned short sidx[EPB];  //  6144 B — permutation
    __shared__ unsigned hist[NCMAX];      // 2 KB each
    __shared__ unsigned incl[NCMAX];
    __shared__ unsigned starts[NCMAX];
    __shared__ unsigned cur[NCMAX];
    __shared__ unsigned base[NCMAX];
    __shared__ unsigned wsum[NCMAX / 64], woff[NCMAX / 64];

    for (int c = threadIdx.x; c < NCMAX; c += APT) hist[c] = 0u;
    __syncthreads();

    const int start = blockIdx.x * EPB;
    int lim = n_edges - start;
    if (lim > EPB) lim = EPB;
    if (lim < 0) lim = 0;

    // pass 1: compute d, write fp32 edge output, stash bf16 payload in LDS
    if (lim == EPB) {
        // full-block fast path: hoist index loads, unroll 3 with batched loads
        const int e0 = start + (int)threadIdx.x;
        int td[3], ts[3];
        td[0] = dst_idx[e0];
        td[1] = dst_idx[e0 + APT];
        td[2] = dst_idx[e0 + 2 * APT];
        ts[0] = src_idx[e0];
        ts[1] = src_idx[e0 + APT];
        ts[2] = src_idx[e0 + 2 * APT];
#pragma unroll
        for (int u = 0; u < 3; ++u) {
            int e = e0 + u * APT;
            int i = (int)threadIdx.x + u * APT;
            int t = td[u];
            int s = ts[u];
            float4 a0  = ea4[(size_t)e * 2 + 0];
            float4 a1  = ea4[(size_t)e * 2 + 1];
            float4 xs0 = x4[(size_t)s * 2 + 0];
            float4 xs1 = x4[(size_t)s * 2 + 1];
            float4 xd0 = x4[(size_t)t * 2 + 0];
            float4 xd1 = x4[(size_t)t * 2 + 1];
            float4 d0, d1;
            d0.x = (xd0.x - xs0.x) / a0.x;
            d0.y = (xd0.y - xs0.y) / a0.y;
            d0.z = (xd0.z - xs0.z) / a0.z;
            d0.w = (xd0.w - xs0.w) / a0.w;
            d1.x = (xd1.x - xs1.x) / a1.x;
            d1.y = (xd1.y - xs1.y) / a1.y;
            d1.z = (xd1.z - xs1.z) / a1.z;
            d1.w = (xd1.w - xs1.w) / a1.w;
            out_edge4[(size_t)e * 2 + 0] = d0;
            out_edge4[(size_t)e * 2 + 1] = d1;
            uint4 v = { pk_bf16(d0.x, d0.y), pk_bf16(d0.z, d0.w),
                        pk_bf16(d1.x, d1.y), pk_bf16(d1.z, d1.w) };
            pay[i] = v;
            key[i] = (unsigned)t;
            atomicAdd(&hist[(unsigned)t >> NPCSH], 1u);
        }
    } else {
        for (int i = threadIdx.x; i < lim; i += APT) {
            int e = start + i;
            int s = src_idx[e];
            int t = dst_idx[e];
            float4 xs0 = x4[(size_t)s * 2 + 0];
            float4 xs1 = x4[(size_t)s * 2 + 1];
            float4 xd0 = x4[(size_t)t * 2 + 0];
            float4 xd1 = x4[(size_t)t * 2 + 1];
            float4 a0  = ea4[(size_t)e * 2 + 0];
            float4 a1  = ea4[(size_t)e * 2 + 1];
            float4 d0, d1;
            d0.x = (xd0.x - xs0.x) / a0.x;
            d0.y = (xd0.y - xs0.y) / a0.y;
            d0.z = (xd0.z - xs0.z) / a0.z;
            d0.w = (xd0.w - xs0.w) / a0.w;
            d1.x = (xd1.x - xs1.x) / a1.x;
            d1.y = (xd1.y - xs1.y) / a1.y;
            d1.z = (xd1.z - xs1.z) / a1.z;
            d1.w = (xd1.w - xs1.w) / a1.w;
            out_edge4[(size_t)e * 2 + 0] = d0;
            out_edge4[(size_t)e * 2 + 1] = d1;
            uint4 v = { pk_bf16(d0.x, d0.y), pk_bf16(d0.z, d0.w),
                        pk_bf16(d1.x, d1.y), pk_bf16(d1.z, d1.w) };
            pay[i] = v;
            key[i] = (unsigned)t;
            atomicAdd(&hist[(unsigned)t >> NPCSH], 1u);
        }
    }
    __syncthreads();

    // exclusive scan of coarse bins
    scan_bins<NCMAX>(hist, incl, starts, cur, wsum, woff);

    // reserve global run space (one atomic per (block, coarse))
    if (threadIdx.x < (unsigned)nc)
        base[threadIdx.x] = hist[threadIdx.x]
            ? atomicAdd(&gcur[threadIdx.x], hist[threadIdx.x]) : 0u;
    __syncthreads();

    // scatter permutation index into sorted order
    for (int i = threadIdx.x; i < lim; i += APT) {
        unsigned c = key[i] >> NPCSH;
        unsigned p = atomicAdd(&cur[c], 1u);
        sidx[p] = (unsigned short)i;
    }
    __syncthreads();

    // write runs coalesced straight from LDS (no global re-read)
    if (lim == EPB) {
        unsigned p0 = threadIdx.x, p1 = p0 + APT, p2 = p1 + APT;
        unsigned i0 = sidx[p0], i1 = sidx[p1], i2 = sidx[p2];
        uint4 v0 = pay[i0], v1 = pay[i1], v2 = pay[i2];
        unsigned t0 = key[i0], t1 = key[i1], t2 = key[i2];
        unsigned c0 = t0 >> NPCSH, c1 = t1 >> NPCSH, c2 = t2 >> NPCSH;
        unsigned a0 = base[c0] + (p0 - starts[c0]);
        unsigned a1 = base[c1] + (p1 - starts[c1]);
        unsigned a2 = base[c2] + (p2 - starts[c2]);
        if (a0 < (unsigned)cap) {
            size_t gi = (size_t)c0 * cap + a0;
            vals[gi] = v0; locs[gi] = (unsigned short)(t0 & (NPC - 1));
        }
        if (a1 < (unsigned)cap) {
            size_t gi = (size_t)c1 * cap + a1;
            vals[gi] = v1; locs[gi] = (unsigned short)(t1 & (NPC - 1));
        }
        if (a2 < (unsigned)cap) {
            size_t gi = (size_t)c2 * cap + a2;
            vals[gi] = v2; locs[gi] = (unsigned short)(t2 & (NPC - 1));
        }
    } else {
        for (int p = threadIdx.x; p < lim; p += APT) {
            unsigned i   = sidx[p];
            unsigned t   = key[i];
            unsigned c   = t >> NPCSH;
            unsigned addr = base[c] + ((unsigned)p - starts[c]);
            if (addr < (unsigned)cap) {
                size_t gi = (size_t)c * cap + addr;
                vals[gi] = pay[i];
                locs[gi] = (unsigned short)(t & (NPC - 1));
            }
        }
    }
}

// =============== coarse-sort path: phase B (round-8, proven ~7 µs) ===============

__global__ __launch_bounds__(BPT) void coarse_reduce_kernel(
    const unsigned* __restrict__ gcur,
    const uint4* __restrict__ vals,
    const unsigned short* __restrict__ locs,
    float4* __restrict__ out_node4,
    int n_nodes, int cap)
{
    __shared__ float acc[NPC * 9];        // 18432 B
    __shared__ uint4 vstage[BCH];         // 24576 B
    __shared__ unsigned hist[NPC];
    __shared__ unsigned incl[NPC];
    __shared__ unsigned starts[NPC];
    __shared__ unsigned cur[NPC];
    __shared__ unsigned wsum[NPC / 64], woff[NPC / 64];

    const int c = blockIdx.x;
    int count = (int)gcur[c];
    if (count > cap) count = cap;
    const uint4* vsrc = vals + (size_t)c * cap;
    const unsigned short* lsrc = locs + (size_t)c * cap;

    for (int j = threadIdx.x; j < NPC * 9; j += BPT) acc[j] = 0.0f;
    __syncthreads();

    for (int cb = 0; cb < count; cb += BCH) {
        int cnt = count - cb;
        if (cnt > BCH) cnt = BCH;

        for (int j = threadIdx.x; j < NPC; j += BPT) hist[j] = 0u;
        __syncthreads();

        uint4 r0, r1;
        unsigned l0 = 0xFFFFu, l1 = 0xFFFFu;
        int i0 = threadIdx.x, i1 = threadIdx.x + BPT;
        if (i0 < cnt) { r0 = vsrc[cb + i0]; l0 = lsrc[cb + i0]; atomicAdd(&hist[l0], 1u); }
        if (i1 < cnt) { r1 = vsrc[cb + i1]; l1 = lsrc[cb + i1]; atomicAdd(&hist[l1], 1u); }
        __syncthreads();

        scan_bins<NPC>(hist, incl, starts, cur, wsum, woff);

        if (l0 != 0xFFFFu) { unsigned p = atomicAdd(&cur[l0], 1u); vstage[p] = r0; }
        if (l1 != 0xFFFFu) { unsigned p = atomicAdd(&cur[l1], 1u); vstage[p] = r1; }
        __syncthreads();

        if (threadIdx.x < NPC) {
            unsigned s = starts[threadIdx.x];
            unsigned e = (threadIdx.x == NPC - 1) ? (unsigned)cnt
                                                  : starts[threadIdx.x + 1];
            if (e > s) {
                float f0 = 0.f, f1 = 0.f, f2 = 0.f, f3 = 0.f;
                float f4 = 0.f, f5 = 0.f, f6 = 0.f, f7 = 0.f;
                for (unsigned j = s; j < e; ++j) {
                    uint4 v = vstage[j];
                    f0 += bf_lo(v.x); f1 += bf_hi(v.x);
                    f2 += bf_lo(v.y); f3 += bf_hi(v.y);
                    f4 += bf_lo(v.z); f5 += bf_hi(v.z);
                    f6 += bf_lo(v.w); f7 += bf_hi(v.w);
                }
                float* a = acc + threadIdx.x * 9;
                a[0] += f0; a[1] += f1; a[2] += f2; a[3] += f3;
                a[4] += f4; a[5] += f5; a[6] += f6; a[7] += f7;
                a[8] += (float)(e - s);
            }
        }
        __syncthreads();
    }

    if (threadIdx.x < NPC) {
        int node = (c << NPCSH) + threadIdx.x;
        if (node < n_nodes) {
            const float* a = acc + threadIdx.x * 9;
            float inv = 1.0f / fmaxf(a[8], 1.0f);
            float4 o0 = { a[0] * inv, a[1] * inv, a[2] * inv, a[3] * inv };
            float4 o1 = { a[4] * inv, a[5] * inv, a[6] * inv, a[7] * inv };
            out_node4[(size_t)node * 2 + 0] = o0;
            out_node4[(size_t)node * 2 + 1] = o1;
        }
    }
}

// =============== pairs path (round-5, proven fallback) ===============

__global__ __launch_bounds__(APT) void edge_phase_kernel(
    const float4* __restrict__ x4,
    const int* __restrict__ src_idx,
    const int* __restrict__ dst_idx,
    const float4* __restrict__ ea4,
    float4* __restrict__ out_edge4,
    unsigned* __restrict__ cursors,
    unsigned* __restrict__ pairs,
    int n_edges, int nb, int cap)
{
    __shared__ unsigned hist[NBMAX];
    __shared__ unsigned base[NBMAX];
    __shared__ unsigned cur[NBMAX];
    __shared__ unsigned tld[EPBF];

    for (int b = threadIdx.x; b < nb; b += APT) { hist[b] = 0u; cur[b] = 0u; }
    __syncthreads();

    const int start = blockIdx.x * EPBF;
    int lim = n_edges - start;
    if (lim > EPBF) lim = EPBF;
    if (lim < 0) lim = 0;

    for (int i = threadIdx.x; i < lim; i += APT) {
        int e = start + i;
        int s = src_idx[e];
        int t = dst_idx[e];
        tld[i] = (unsigned)t;
        float4 xs0 = x4[(size_t)s * 2 + 0];
        float4 xs1 = x4[(size_t)s * 2 + 1];
        float4 xd0 = x4[(size_t)t * 2 + 0];
        float4 xd1 = x4[(size_t)t * 2 + 1];
        float4 a0  = ea4[(size_t)e * 2 + 0];
        float4 a1  = ea4[(size_t)e * 2 + 1];
        float4 d0, d1;
        d0.x = (xd0.x - xs0.x) / a0.x;
        d0.y = (xd0.y - xs0.y) / a0.y;
        d0.z = (xd0.z - xs0.z) / a0.z;
        d0.w = (xd0.w - xs0.w) / a0.w;
        d1.x = (xd1.x - xs1.x) / a1.x;
        d1.y = (xd1.y - xs1.y) / a1.y;
        d1.z = (xd1.z - xs1.z) / a1.z;
        d1.w = (xd1.w - xs1.w) / a1.w;
        out_edge4[(size_t)e * 2 + 0] = d0;
        out_edge4[(size_t)e * 2 + 1] = d1;
        atomicAdd(&hist[t >> BSH], 1u);
    }
    __syncthreads();

    for (int b = threadIdx.x; b < nb; b += APT)
        base[b] = hist[b] ? atomicAdd(&cursors[b], hist[b]) : 0u;
    __syncthreads();

    for (int i = threadIdx.x; i < lim; i += APT) {
        int e = start + i;
        unsigned t = tld[i];
        unsigned b = t >> BSH;
        unsigned p = base[b] + atomicAdd(&cur[b], 1u);
        if (p < (unsigned)cap)
            pairs[(size_t)b * cap + p] = ((unsigned)e << BSH) | (t & BMASK);
    }
}

__device__ __forceinline__ void acc9(float* __restrict__ acc, unsigned loc,
                                     float4 d0, float4 d1) {
    float* a = acc + loc * 9;
    atomicAdd(a + 0, d0.x);
    atomicAdd(a + 1, d0.y);
    atomicAdd(a + 2, d0.z);
    atomicAdd(a + 3, d0.w);
    atomicAdd(a + 4, d1.x);
    atomicAdd(a + 5, d1.y);
    atomicAdd(a + 6, d1.z);
    atomicAdd(a + 7, d1.w);
    atomicAdd(a + 8, 1.0f);
}

__global__ __launch_bounds__(RPT5) void bucket_reduce_kernel(
    const unsigned* __restrict__ cursors,
    const unsigned* __restrict__ pairs,
    const float4* __restrict__ edge4,
    float4* __restrict__ out_node4,
    int n_nodes, int cap)
{
    __shared__ float acc[64 * 9];
    for (int j = threadIdx.x; j < 64 * 9; j += RPT5) acc[j] = 0.0f;
    __syncthreads();

    const int b = blockIdx.x;
    int count = (int)cursors[b];
    if (count > cap) count = cap;
    const unsigned* pb = pairs + (size_t)b * cap;

    for (int i = threadIdx.x; i < count; i += RPT5) {
        unsigned pr = pb[i];
        float4 d0 = edge4[(size_t)(pr >> BSH) * 2 + 0];
        float4 d1 = edge4[(size_t)(pr >> BSH) * 2 + 1];
        acc9(acc, pr & BMASK, d0, d1);
    }
    __syncthreads();

    if (threadIdx.x < 128) {
        int loc  = threadIdx.x >> 1;
        int half = threadIdx.x & 1;
        int node = (b << BSH) + loc;
        if (node < n_nodes) {
            const float* a = acc + loc * 9;
            float inv = 1.0f / fmaxf(a[8], 1.0f);
            float4 o = { a[half * 4 + 0] * inv, a[half * 4 + 1] * inv,
                         a[half * 4 + 2] * inv, a[half * 4 + 3] * inv };
            out_node4[(size_t)node * 2 + half] = o;
        }
    }
}

// =============== atomic fallback (round-2, proven) ===============

__global__ void fb_zero_kernel(float* __restrict__ node_out, int n_node_f,
                               float* __restrict__ counts, int n_counts) {
    int stride = gridDim.x * blockDim.x;
    int tid = blockIdx.x * blockDim.x + threadIdx.x;
    for (int i = tid; i < n_node_f; i += stride) node_out[i] = 0.0f;
    for (int i = tid; i < n_counts; i += stride) counts[i] = 0.0f;
}

__global__ void fb_edge_kernel(const float4* __restrict__ x4,
                               const int* __restrict__ src_idx,
                               const int* __restrict__ dst_idx,
                               const float4* __restrict__ ea4,
                               float4* __restrict__ out_edge4,
                               float* __restrict__ node_sums,
                               float* __restrict__ counts,
                               int n_edges) {
    int e = blockIdx.x * blockDim.x + threadIdx.x;
    if (e >= n_edges) return;
    int s = src_idx[e];
    int t = dst_idx[e];
    float4 xs0 = x4[(size_t)s * 2 + 0];
    float4 xs1 = x4[(size_t)s * 2 + 1];
    float4 xd0 = x4[(size_t)t * 2 + 0];
    float4 xd1 = x4[(size_t)t * 2 + 1];
    float4 a0  = ea4[(size_t)e * 2 + 0];
    float4 a1  = ea4[(size_t)e * 2 + 1];
    float4 d0, d1;
    d0.x = (xd0.x - xs0.x) / a0.x;
    d0.y = (xd0.y - xs0.y) / a0.y;
    d0.z = (xd0.z - xs0.z) / a0.z;
    d0.w = (xd0.w - xs0.w) / a0.w;
    d1.x = (xd1.x - xs1.x) / a1.x;
    d1.y = (xd1.y - xs1.y) / a1.y;
    d1.z = (xd1.z - xs1.z) / a1.z;
    d1.w = (xd1.w - xs1.w) / a1.w;
    out_edge4[(size_t)e * 2 + 0] = d0;
    out_edge4[(size_t)e * 2 + 1] = d1;
    float* sp = node_sums + (size_t)t * D;
    atomicAdd(sp + 0, d0.x);
    atomicAdd(sp + 1, d0.y);
    atomicAdd(sp + 2, d0.z);
    atomicAdd(sp + 3, d0.w);
    atomicAdd(sp + 4, d1.x);
    atomicAdd(sp + 5, d1.y);
    atomicAdd(sp + 6, d1.z);
    atomicAdd(sp + 7, d1.w);
    atomicAdd(counts + t, 1.0f);
}

__global__ void fb_node_kernel(float4* __restrict__ node4,
                               const float* __restrict__ counts,
                               int n_nodes) {
    int n = blockIdx.x * blockDim.x + threadIdx.x;
    if (n >= n_nodes) return;
    float inv = 1.0f / fmaxf(counts[n], 1.0f);
    float4 s0 = node4[(size_t)n * 2 + 0];
    float4 s1 = node4[(size_t)n * 2 + 1];
    s0.x *= inv; s0.y *= inv; s0.z *= inv; s0.w *= inv;
    s1.x *= inv; s1.y *= inv; s1.z *= inv; s1.w *= inv;
    node4[(size_t)n * 2 + 0] = s0;
    node4[(size_t)n * 2 + 1] = s1;
}

// ---------------- launch ----------------

extern "C" void kernel_launch(void* const* d_in, const int* in_sizes, int n_in,
                              void* d_out, int out_size, void* d_ws, size_t ws_size,
                              hipStream_t stream) {
    const float* x  = (const float*)d_in[0];
    const int*   ei = (const int*)d_in[1];
    const float* ea = (const float*)d_in[2];

    const int n_nodes = in_sizes[0] / D;
    const int n_edges = in_sizes[2] / D;

    const int* src_idx = ei;
    const int* dst_idx = ei + n_edges;

    float* out_node = (float*)d_out;
    float* out_edge = out_node + (size_t)n_nodes * D;

    // --- coarse-sort fast path ---
    {
        const int nc = (n_nodes + NPC - 1) >> NPCSH;
        long long meanc = nc > 0 ? (long long)n_edges / nc : 0;
        int capc = (int)(meanc + meanc / 8 + 1024);
        size_t gcur_b = ((size_t)nc * 4 + 255) & ~(size_t)255;
        size_t vals_b = (size_t)nc * capc * 16;
        size_t locs_b = (size_t)nc * capc * 2;
        size_t need = gcur_b + vals_b + locs_b + 256;

        if (nc >= 1 && nc <= NCMAX && ws_size >= need) {
            unsigned*       gcur = (unsigned*)d_ws;
            uint4*          vals = (uint4*)((char*)d_ws + gcur_b);
            unsigned short* locs = (unsigned short*)((char*)d_ws + gcur_b + vals_b);

            int blocksA = (n_edges + EPB - 1) / EPB;
            zero_cursors_kernel<<<(nc + 255) / 256, 256, 0, stream>>>(gcur, nc);
            edge_sort3_kernel<<<blocksA, APT, 0, stream>>>(
                (const float4*)x, src_idx, dst_idx, (const float4*)ea,
                (float4*)out_edge, gcur, vals, locs, n_edges, nc, capc);
            coarse_reduce_kernel<<<nc, BPT, 0, stream>>>(
                gcur, vals, locs, (float4*)out_node, n_nodes, capc);
            return;
        }
    }

    // --- pairs path (round-5) ---
    {
        const int nb = (n_nodes + BMASK) >> BSH;
        int cap = (int)(((long long)n_edges / (nb > 0 ? nb : 1) + 256) * 3 / 2);
        cap = (cap + 3) & ~3;
        size_t cursors_bytes = ((size_t)nb * 4 + 255) & ~(size_t)255;
        size_t need = cursors_bytes + (size_t)nb * cap * 4;
        if (nb <= NBMAX && ws_size >= need) {
            unsigned* cursors = (unsigned*)d_ws;
            unsigned* pairs   = (unsigned*)((char*)d_ws + cursors_bytes);

            int blocksA = (n_edges + EPBF - 1) / EPBF;
            zero_cursors_kernel<<<(nb + 255) / 256, 256, 0, stream>>>(cursors, nb);
            edge_phase_kernel<<<blocksA, APT, 0, stream>>>(
                (const float4*)x, src_idx, dst_idx, (const float4*)ea,
                (float4*)out_edge, cursors, pairs, n_edges, nb, cap);
            bucket_reduce_kernel<<<nb, RPT5, 0, stream>>>(
                cursors, pairs, (const float4*)out_edge, (float4*)out_node,
                n_nodes, cap);
            return;
        }
    }

    // --- atomic fallback ---
    {
        float* counts = (float*)d_ws;
        int n = n_nodes * D;
        int blocks = (n + 255) / 256;
        if (blocks > 2048) blocks = 2048;
        fb_zero_kernel<<<blocks, 256, 0, stream>>>(out_node, n, counts, n_nodes);
        fb_edge_kernel<<<(n_edges + 255) / 256, 256, 0, stream>>>(
            (const float4*)x, src_idx, dst_idx, (const float4*)ea,
            (float4*)out_edge, out_node, counts, n_edges);
        fb_node_kernel<<<(n_nodes + 255) / 256, 256, 0, stream>>>(
            (float4*)out_node, counts, n_nodes);
    }
}

// Round 11
// 174.573 us; speedup vs baseline: 1.0033x; 1.0033x over previous
//
#include <hip/hip_runtime.h>
#include <math.h>

#define D 8
// ---- coarse-sort fast path ----
#define NPC 512            // nodes per coarse bucket (power of 2)
#define NPCSH 9
#define NCMAX 512          // max coarse buckets on fast path
#define EPB 3072           // edges per sort-kernel block
#define APT 1024           // sort-kernel threads
#define BCH 1536           // phase-B chunk (records)
#define BPT 1024           // phase-B threads
// ---- pairs fallback path ----
#define BSH 6
#define BMASK 63
#define NBMAX 1600
#define EPBF 6250          // fallback pairs-path edges per block
#define RPT5 512

// ---- bf16 helpers ----
__device__ __forceinline__ unsigned pk_bf16(float a, float b) {
    unsigned ua = __float_as_uint(a), ub = __float_as_uint(b);
    ua = (ua + 0x7FFFu + ((ua >> 16) & 1u)) >> 16;   // RTNE
    ub = (ub + 0x7FFFu + ((ub >> 16) & 1u)) >> 16;
    return ua | (ub << 16);
}
__device__ __forceinline__ float bf_lo(unsigned u) { return __uint_as_float(u << 16); }
__device__ __forceinline__ float bf_hi(unsigned u) { return __uint_as_float(u & 0xFFFF0000u); }

__global__ void zero_cursors_kernel(unsigned* __restrict__ cur, int n) {
    int i = blockIdx.x * blockDim.x + threadIdx.x;
    if (i < n) cur[i] = 0u;
}

// block-wide exclusive scan over NB bins (NB multiple of 64, <= blockDim)
template<int NB>
__device__ __forceinline__ void scan_bins(unsigned* hist, unsigned* incl,
                                          unsigned* starts, unsigned* cur,
                                          unsigned* wsum, unsigned* woff) {
    int tid = threadIdx.x;
    if (tid < NB) {
        int l = tid & 63;
        unsigned v = hist[tid], s = v;
#pragma unroll
        for (int dd = 1; dd < 64; dd <<= 1) {
            unsigned tt = __shfl_up(s, dd, 64);
            if (l >= dd) s += tt;
        }
        incl[tid] = s;
        if (l == 63) wsum[tid >> 6] = s;
    }
    __syncthreads();
    if (tid == 0) {
        unsigned o = 0;
#pragma unroll
        for (int w = 0; w < NB / 64; ++w) { woff[w] = o; o += wsum[w]; }
    }
    __syncthreads();
    if (tid < NB) {
        unsigned st = incl[tid] - hist[tid] + woff[tid >> 6];
        starts[tid] = st;
        cur[tid] = st;
    }
    __syncthreads();
}

// =============== K1: pure gather/compute (no LDS, max TLP) ===============

__global__ __launch_bounds__(256) void edge_compute_kernel(
    const float4* __restrict__ x4,
    const int* __restrict__ src_idx,
    const int* __restrict__ dst_idx,
    const float4* __restrict__ ea4,
    float4* __restrict__ out_edge4,
    int n_edges)
{
    int e = blockIdx.x * 256 + threadIdx.x;
    if (e >= n_edges) return;
    int s = src_idx[e];
    int t = dst_idx[e];
    float4 xs0 = x4[(size_t)s * 2 + 0];
    float4 xs1 = x4[(size_t)s * 2 + 1];
    float4 xd0 = x4[(size_t)t * 2 + 0];
    float4 xd1 = x4[(size_t)t * 2 + 1];
    float4 a0  = ea4[(size_t)e * 2 + 0];
    float4 a1  = ea4[(size_t)e * 2 + 1];
    float4 d0, d1;
    d0.x = (xd0.x - xs0.x) / a0.x;
    d0.y = (xd0.y - xs0.y) / a0.y;
    d0.z = (xd0.z - xs0.z) / a0.z;
    d0.w = (xd0.w - xs0.w) / a0.w;
    d1.x = (xd1.x - xs1.x) / a1.x;
    d1.y = (xd1.y - xs1.y) / a1.y;
    d1.z = (xd1.z - xs1.z) / a1.z;
    d1.w = (xd1.w - xs1.w) / a1.w;
    out_edge4[(size_t)e * 2 + 0] = d0;
    out_edge4[(size_t)e * 2 + 1] = d1;
}

// =============== K2: streaming counting-sort into coarse regions ===============

__global__ __launch_bounds__(APT) void edge_sortk_kernel(
    const int* __restrict__ dst_idx,
    const float4* __restrict__ edge4,
    unsigned* __restrict__ gcur,          // [nc]
    uint4* __restrict__ vals,             // [nc*cap]
    unsigned short* __restrict__ locs,    // [nc*cap]
    int n_edges, int nc, int cap)
{
    __shared__ uint4 pay[EPB];            // 49152 B — bf16 payload (sorted order)
    __shared__ unsigned meta[EPB];        // 12288 B — node id (sorted order)
    __shared__ unsigned hist[NCMAX];
    __shared__ unsigned incl[NCMAX];
    __shared__ unsigned starts[NCMAX];
    __shared__ unsigned cur[NCMAX];
    __shared__ unsigned base[NCMAX];
    __shared__ unsigned wsum[NCMAX / 64], woff[NCMAX / 64];

    for (int c = threadIdx.x; c < NCMAX; c += APT) hist[c] = 0u;
    __syncthreads();

    const int start = blockIdx.x * EPB;
    int lim = n_edges - start;
    if (lim > EPB) lim = EPB;
    if (lim < 0) lim = 0;

    // pass A: histogram of coarse buckets (dst streaming read)
    for (int i = threadIdx.x; i < lim; i += APT) {
        unsigned t = (unsigned)dst_idx[start + i];
        atomicAdd(&hist[t >> NPCSH], 1u);
    }
    __syncthreads();

    scan_bins<NCMAX>(hist, incl, starts, cur, wsum, woff);

    // reserve global run space (pass B/C don't race with this: base read after sync)
    if (threadIdx.x < (unsigned)nc)
        base[threadIdx.x] = hist[threadIdx.x]
            ? atomicAdd(&gcur[threadIdx.x], hist[threadIdx.x]) : 0u;

    // pass B: stream edge_deriv (coalesced), convert bf16, direct-scatter into
    // sorted LDS position (no sidx indirection)
    for (int i = threadIdx.x; i < lim; i += APT) {
        int e = start + i;
        unsigned t = (unsigned)dst_idx[e];      // L2-hot re-read
        float4 d0 = edge4[(size_t)e * 2 + 0];
        float4 d1 = edge4[(size_t)e * 2 + 1];
        unsigned p = atomicAdd(&cur[t >> NPCSH], 1u);
        uint4 v = { pk_bf16(d0.x, d0.y), pk_bf16(d0.z, d0.w),
                    pk_bf16(d1.x, d1.y), pk_bf16(d1.z, d1.w) };
        pay[p] = v;
        meta[p] = t;
    }
    __syncthreads();

    // pass C: coalesced LDS read -> coalesced global run write
    for (int p = threadIdx.x; p < lim; p += APT) {
        unsigned t = meta[p];
        unsigned c = t >> NPCSH;
        unsigned addr = base[c] + ((unsigned)p - starts[c]);
        if (addr < (unsigned)cap) {
            size_t gi = (size_t)c * cap + addr;
            vals[gi] = pay[p];
            locs[gi] = (unsigned short)(t & (NPC - 1));
        }
    }
}

// =============== K3: coarse reduce (round-8, proven ~7 µs) ===============

__global__ __launch_bounds__(BPT) void coarse_reduce_kernel(
    const unsigned* __restrict__ gcur,
    const uint4* __restrict__ vals,
    const unsigned short* __restrict__ locs,
    float4* __restrict__ out_node4,
    int n_nodes, int cap)
{
    __shared__ float acc[NPC * 9];        // 18432 B
    __shared__ uint4 vstage[BCH];         // 24576 B
    __shared__ unsigned hist[NPC];
    __shared__ unsigned incl[NPC];
    __shared__ unsigned starts[NPC];
    __shared__ unsigned cur[NPC];
    __shared__ unsigned wsum[NPC / 64], woff[NPC / 64];

    const int c = blockIdx.x;
    int count = (int)gcur[c];
    if (count > cap) count = cap;
    const uint4* vsrc = vals + (size_t)c * cap;
    const unsigned short* lsrc = locs + (size_t)c * cap;

    for (int j = threadIdx.x; j < NPC * 9; j += BPT) acc[j] = 0.0f;
    __syncthreads();

    for (int cb = 0; cb < count; cb += BCH) {
        int cnt = count - cb;
        if (cnt > BCH) cnt = BCH;

        for (int j = threadIdx.x; j < NPC; j += BPT) hist[j] = 0u;
        __syncthreads();

        uint4 r0, r1;
        unsigned l0 = 0xFFFFu, l1 = 0xFFFFu;
        int i0 = threadIdx.x, i1 = threadIdx.x + BPT;
        if (i0 < cnt) { r0 = vsrc[cb + i0]; l0 = lsrc[cb + i0]; atomicAdd(&hist[l0], 1u); }
        if (i1 < cnt) { r1 = vsrc[cb + i1]; l1 = lsrc[cb + i1]; atomicAdd(&hist[l1], 1u); }
        __syncthreads();

        scan_bins<NPC>(hist, incl, starts, cur, wsum, woff);

        if (l0 != 0xFFFFu) { unsigned p = atomicAdd(&cur[l0], 1u); vstage[p] = r0; }
        if (l1 != 0xFFFFu) { unsigned p = atomicAdd(&cur[l1], 1u); vstage[p] = r1; }
        __syncthreads();

        if (threadIdx.x < NPC) {
            unsigned s = starts[threadIdx.x];
            unsigned e = (threadIdx.x == NPC - 1) ? (unsigned)cnt
                                                  : starts[threadIdx.x + 1];
            if (e > s) {
                float f0 = 0.f, f1 = 0.f, f2 = 0.f, f3 = 0.f;
                float f4 = 0.f, f5 = 0.f, f6 = 0.f, f7 = 0.f;
                for (unsigned j = s; j < e; ++j) {
                    uint4 v = vstage[j];
                    f0 += bf_lo(v.x); f1 += bf_hi(v.x);
                    f2 += bf_lo(v.y); f3 += bf_hi(v.y);
                    f4 += bf_lo(v.z); f5 += bf_hi(v.z);
                    f6 += bf_lo(v.w); f7 += bf_hi(v.w);
                }
                float* a = acc + threadIdx.x * 9;
                a[0] += f0; a[1] += f1; a[2] += f2; a[3] += f3;
                a[4] += f4; a[5] += f5; a[6] += f6; a[7] += f7;
                a[8] += (float)(e - s);
            }
        }
        __syncthreads();
    }

    if (threadIdx.x < NPC) {
        int node = (c << NPCSH) + threadIdx.x;
        if (node < n_nodes) {
            const float* a = acc + threadIdx.x * 9;
            float inv = 1.0f / fmaxf(a[8], 1.0f);
            float4 o0 = { a[0] * inv, a[1] * inv, a[2] * inv, a[3] * inv };
            float4 o1 = { a[4] * inv, a[5] * inv, a[6] * inv, a[7] * inv };
            out_node4[(size_t)node * 2 + 0] = o0;
            out_node4[(size_t)node * 2 + 1] = o1;
        }
    }
}

// =============== pairs path (round-5, proven fallback) ===============

__global__ __launch_bounds__(APT) void edge_phase_kernel(
    const float4* __restrict__ x4,
    const int* __restrict__ src_idx,
    const int* __restrict__ dst_idx,
    const float4* __restrict__ ea4,
    float4* __restrict__ out_edge4,
    unsigned* __restrict__ cursors,
    unsigned* __restrict__ pairs,
    int n_edges, int nb, int cap)
{
    __shared__ unsigned hist[NBMAX];
    __shared__ unsigned base[NBMAX];
    __shared__ unsigned cur[NBMAX];
    __shared__ unsigned tld[EPBF];

    for (int b = threadIdx.x; b < nb; b += APT) { hist[b] = 0u; cur[b] = 0u; }
    __syncthreads();

    const int start = blockIdx.x * EPBF;
    int lim = n_edges - start;
    if (lim > EPBF) lim = EPBF;
    if (lim < 0) lim = 0;

    for (int i = threadIdx.x; i < lim; i += APT) {
        int e = start + i;
        int s = src_idx[e];
        int t = dst_idx[e];
        tld[i] = (unsigned)t;
        float4 xs0 = x4[(size_t)s * 2 + 0];
        float4 xs1 = x4[(size_t)s * 2 + 1];
        float4 xd0 = x4[(size_t)t * 2 + 0];
        float4 xd1 = x4[(size_t)t * 2 + 1];
        float4 a0  = ea4[(size_t)e * 2 + 0];
        float4 a1  = ea4[(size_t)e * 2 + 1];
        float4 d0, d1;
        d0.x = (xd0.x - xs0.x) / a0.x;
        d0.y = (xd0.y - xs0.y) / a0.y;
        d0.z = (xd0.z - xs0.z) / a0.z;
        d0.w = (xd0.w - xs0.w) / a0.w;
        d1.x = (xd1.x - xs1.x) / a1.x;
        d1.y = (xd1.y - xs1.y) / a1.y;
        d1.z = (xd1.z - xs1.z) / a1.z;
        d1.w = (xd1.w - xs1.w) / a1.w;
        out_edge4[(size_t)e * 2 + 0] = d0;
        out_edge4[(size_t)e * 2 + 1] = d1;
        atomicAdd(&hist[t >> BSH], 1u);
    }
    __syncthreads();

    for (int b = threadIdx.x; b < nb; b += APT)
        base[b] = hist[b] ? atomicAdd(&cursors[b], hist[b]) : 0u;
    __syncthreads();

    for (int i = threadIdx.x; i < lim; i += APT) {
        int e = start + i;
        unsigned t = tld[i];
        unsigned b = t >> BSH;
        unsigned p = base[b] + atomicAdd(&cur[b], 1u);
        if (p < (unsigned)cap)
            pairs[(size_t)b * cap + p] = ((unsigned)e << BSH) | (t & BMASK);
    }
}

__device__ __forceinline__ void acc9(float* __restrict__ acc, unsigned loc,
                                     float4 d0, float4 d1) {
    float* a = acc + loc * 9;
    atomicAdd(a + 0, d0.x);
    atomicAdd(a + 1, d0.y);
    atomicAdd(a + 2, d0.z);
    atomicAdd(a + 3, d0.w);
    atomicAdd(a + 4, d1.x);
    atomicAdd(a + 5, d1.y);
    atomicAdd(a + 6, d1.z);
    atomicAdd(a + 7, d1.w);
    atomicAdd(a + 8, 1.0f);
}

__global__ __launch_bounds__(RPT5) void bucket_reduce_kernel(
    const unsigned* __restrict__ cursors,
    const unsigned* __restrict__ pairs,
    const float4* __restrict__ edge4,
    float4* __restrict__ out_node4,
    int n_nodes, int cap)
{
    __shared__ float acc[64 * 9];
    for (int j = threadIdx.x; j < 64 * 9; j += RPT5) acc[j] = 0.0f;
    __syncthreads();

    const int b = blockIdx.x;
    int count = (int)cursors[b];
    if (count > cap) count = cap;
    const unsigned* pb = pairs + (size_t)b * cap;

    for (int i = threadIdx.x; i < count; i += RPT5) {
        unsigned pr = pb[i];
        float4 d0 = edge4[(size_t)(pr >> BSH) * 2 + 0];
        float4 d1 = edge4[(size_t)(pr >> BSH) * 2 + 1];
        acc9(acc, pr & BMASK, d0, d1);
    }
    __syncthreads();

    if (threadIdx.x < 128) {
        int loc  = threadIdx.x >> 1;
        int half = threadIdx.x & 1;
        int node = (b << BSH) + loc;
        if (node < n_nodes) {
            const float* a = acc + loc * 9;
            float inv = 1.0f / fmaxf(a[8], 1.0f);
            float4 o = { a[half * 4 + 0] * inv, a[half * 4 + 1] * inv,
                         a[half * 4 + 2] * inv, a[half * 4 + 3] * inv };
            out_node4[(size_t)node * 2 + half] = o;
        }
    }
}

// =============== atomic fallback (round-2, proven) ===============

__global__ void fb_zero_kernel(float* __restrict__ node_out, int n_node_f,
                               float* __restrict__ counts, int n_counts) {
    int stride = gridDim.x * blockDim.x;
    int tid = blockIdx.x * blockDim.x + threadIdx.x;
    for (int i = tid; i < n_node_f; i += stride) node_out[i] = 0.0f;
    for (int i = tid; i < n_counts; i += stride) counts[i] = 0.0f;
}

__global__ void fb_edge_kernel(const float4* __restrict__ x4,
                               const int* __restrict__ src_idx,
                               const int* __restrict__ dst_idx,
                               const float4* __restrict__ ea4,
                               float4* __restrict__ out_edge4,
                               float* __restrict__ node_sums,
                               float* __restrict__ counts,
                               int n_edges) {
    int e = blockIdx.x * blockDim.x + threadIdx.x;
    if (e >= n_edges) return;
    int s = src_idx[e];
    int t = dst_idx[e];
    float4 xs0 = x4[(size_t)s * 2 + 0];
    float4 xs1 = x4[(size_t)s * 2 + 1];
    float4 xd0 = x4[(size_t)t * 2 + 0];
    float4 xd1 = x4[(size_t)t * 2 + 1];
    float4 a0  = ea4[(size_t)e * 2 + 0];
    float4 a1  = ea4[(size_t)e * 2 + 1];
    float4 d0, d1;
    d0.x = (xd0.x - xs0.x) / a0.x;
    d0.y = (xd0.y - xs0.y) / a0.y;
    d0.z = (xd0.z - xs0.z) / a0.z;
    d0.w = (xd0.w - xs0.w) / a0.w;
    d1.x = (xd1.x - xs1.x) / a1.x;
    d1.y = (xd1.y - xs1.y) / a1.y;
    d1.z = (xd1.z - xs1.z) / a1.z;
    d1.w = (xd1.w - xs1.w) / a1.w;
    out_edge4[(size_t)e * 2 + 0] = d0;
    out_edge4[(size_t)e * 2 + 1] = d1;
    float* sp = node_sums + (size_t)t * D;
    atomicAdd(sp + 0, d0.x);
    atomicAdd(sp + 1, d0.y);
    atomicAdd(sp + 2, d0.z);
    atomicAdd(sp + 3, d0.w);
    atomicAdd(sp + 4, d1.x);
    atomicAdd(sp + 5, d1.y);
    atomicAdd(sp + 6, d1.z);
    atomicAdd(sp + 7, d1.w);
    atomicAdd(counts + t, 1.0f);
}

__global__ void fb_node_kernel(float4* __restrict__ node4,
                               const float* __restrict__ counts,
                               int n_nodes) {
    int n = blockIdx.x * blockDim.x + threadIdx.x;
    if (n >= n_nodes) return;
    float inv = 1.0f / fmaxf(counts[n], 1.0f);
    float4 s0 = node4[(size_t)n * 2 + 0];
    float4 s1 = node4[(size_t)n * 2 + 1];
    s0.x *= inv; s0.y *= inv; s0.z *= inv; s0.w *= inv;
    s1.x *= inv; s1.y *= inv; s1.z *= inv; s1.w *= inv;
    node4[(size_t)n * 2 + 0] = s0;
    node4[(size_t)n * 2 + 1] = s1;
}

// ---------------- launch ----------------

extern "C" void kernel_launch(void* const* d_in, const int* in_sizes, int n_in,
                              void* d_out, int out_size, void* d_ws, size_t ws_size,
                              hipStream_t stream) {
    const float* x  = (const float*)d_in[0];
    const int*   ei = (const int*)d_in[1];
    const float* ea = (const float*)d_in[2];

    const int n_nodes = in_sizes[0] / D;
    const int n_edges = in_sizes[2] / D;

    const int* src_idx = ei;
    const int* dst_idx = ei + n_edges;

    float* out_node = (float*)d_out;
    float* out_edge = out_node + (size_t)n_nodes * D;

    // --- split coarse-sort fast path ---
    {
        const int nc = (n_nodes + NPC - 1) >> NPCSH;
        long long meanc = nc > 0 ? (long long)n_edges / nc : 0;
        int capc = (int)(meanc + meanc / 8 + 1024);
        size_t gcur_b = ((size_t)nc * 4 + 255) & ~(size_t)255;
        size_t vals_b = (size_t)nc * capc * 16;
        size_t locs_b = (size_t)nc * capc * 2;
        size_t need = gcur_b + vals_b + locs_b + 256;

        if (nc >= 1 && nc <= NCMAX && ws_size >= need) {
            unsigned*       gcur = (unsigned*)d_ws;
            uint4*          vals = (uint4*)((char*)d_ws + gcur_b);
            unsigned short* locs = (unsigned short*)((char*)d_ws + gcur_b + vals_b);

            zero_cursors_kernel<<<(nc + 255) / 256, 256, 0, stream>>>(gcur, nc);
            edge_compute_kernel<<<(n_edges + 255) / 256, 256, 0, stream>>>(
                (const float4*)x, src_idx, dst_idx, (const float4*)ea,
                (float4*)out_edge, n_edges);
            int blocksS = (n_edges + EPB - 1) / EPB;
            edge_sortk_kernel<<<blocksS, APT, 0, stream>>>(
                dst_idx, (const float4*)out_edge, gcur, vals, locs,
                n_edges, nc, capc);
            coarse_reduce_kernel<<<nc, BPT, 0, stream>>>(
                gcur, vals, locs, (float4*)out_node, n_nodes, capc);
            return;
        }
    }

    // --- pairs path (round-5) ---
    {
        const int nb = (n_nodes + BMASK) >> BSH;
        int cap = (int)(((long long)n_edges / (nb > 0 ? nb : 1) + 256) * 3 / 2);
        cap = (cap + 3) & ~3;
        size_t cursors_bytes = ((size_t)nb * 4 + 255) & ~(size_t)255;
        size_t need = cursors_bytes + (size_t)nb * cap * 4;
        if (nb <= NBMAX && ws_size >= need) {
            unsigned* cursors = (unsigned*)d_ws;
            unsigned* pairs   = (unsigned*)((char*)d_ws + cursors_bytes);

            int blocksA = (n_edges + EPBF - 1) / EPBF;
            zero_cursors_kernel<<<(nb + 255) / 256, 256, 0, stream>>>(cursors, nb);
            edge_phase_kernel<<<blocksA, APT, 0, stream>>>(
                (const float4*)x, src_idx, dst_idx, (const float4*)ea,
                (float4*)out_edge, cursors, pairs, n_edges, nb, cap);
            bucket_reduce_kernel<<<nb, RPT5, 0, stream>>>(
                cursors, pairs, (const float4*)out_edge, (float4*)out_node,
                n_nodes, cap);
            return;
        }
    }

    // --- atomic fallback ---
    {
        float* counts = (float*)d_ws;
        int n = n_nodes * D;
        int blocks = (n + 255) / 256;
        if (blocks > 2048) blocks = 2048;
        fb_zero_kernel<<<blocks, 256, 0, stream>>>(out_node, n, counts, n_nodes);
        fb_edge_kernel<<<(n_edges + 255) / 256, 256, 0, stream>>>(
            (const float4*)x, src_idx, dst_idx, (const float4*)ea,
            (float4*)out_edge, out_node, counts, n_edges);
        fb_node_kernel<<<(n_nodes + 255) / 256, 256, 0, stream>>>(
            (float4*)out_node, counts, n_nodes);
    }
}

// Round 12
// 160.799 us; speedup vs baseline: 1.0893x; 1.0857x over previous
//
#include <hip/hip_runtime.h>
#include <math.h>

#define D 8
// ---- coarse-sort fast path ----
#define NPC 512            // nodes per coarse bucket (power of 2)
#define NPCSH 9
#define NCMAX 512          // max coarse buckets on fast path
#define EPB 3072           // edges per sort-kernel block
#define APT 1024           // sort-kernel threads
#define BCH 1536           // phase-B chunk (records)
#define BPT 1024           // phase-B threads
// ---- pairs fallback path ----
#define BSH 6
#define BMASK 63
#define NBMAX 1600
#define EPBF 6250          // fallback pairs-path edges per block
#define RPT5 512

// ---- bf16 helpers ----
__device__ __forceinline__ unsigned pk_bf16(float a, float b) {
    unsigned ua = __float_as_uint(a), ub = __float_as_uint(b);
    ua = (ua + 0x7FFFu + ((ua >> 16) & 1u)) >> 16;   // RTNE
    ub = (ub + 0x7FFFu + ((ub >> 16) & 1u)) >> 16;
    return ua | (ub << 16);
}
__device__ __forceinline__ float bf_lo(unsigned u) { return __uint_as_float(u << 16); }
__device__ __forceinline__ float bf_hi(unsigned u) { return __uint_as_float(u & 0xFFFF0000u); }

__global__ void zero_cursors_kernel(unsigned* __restrict__ cur, int n) {
    int i = blockIdx.x * blockDim.x + threadIdx.x;
    if (i < n) cur[i] = 0u;
}

// block-wide exclusive scan over NB bins (NB multiple of 64, <= blockDim)
template<int NB>
__device__ __forceinline__ void scan_bins(unsigned* hist, unsigned* incl,
                                          unsigned* starts, unsigned* cur,
                                          unsigned* wsum, unsigned* woff) {
    int tid = threadIdx.x;
    if (tid < NB) {
        int l = tid & 63;
        unsigned v = hist[tid], s = v;
#pragma unroll
        for (int dd = 1; dd < 64; dd <<= 1) {
            unsigned tt = __shfl_up(s, dd, 64);
            if (l >= dd) s += tt;
        }
        incl[tid] = s;
        if (l == 63) wsum[tid >> 6] = s;
    }
    __syncthreads();
    if (tid == 0) {
        unsigned o = 0;
#pragma unroll
        for (int w = 0; w < NB / 64; ++w) { woff[w] = o; o += wsum[w]; }
    }
    __syncthreads();
    if (tid < NB) {
        unsigned st = incl[tid] - hist[tid] + woff[tid >> 6];
        starts[tid] = st;
        cur[tid] = st;
    }
    __syncthreads();
}

// =============== K1: gather/compute, 2 lanes per edge (merged-line gathers) ===============

__global__ __launch_bounds__(256) void edge_compute2_kernel(
    const float4* __restrict__ x4,
    const int* __restrict__ src_idx,
    const int* __restrict__ dst_idx,
    const float4* __restrict__ ea4,
    float4* __restrict__ out_edge4,
    int n_edges)
{
    int tid = blockIdx.x * 256 + threadIdx.x;
    int e = tid >> 1;          // 2 lanes per edge
    int h = tid & 1;           // low/high float4 half
    if (e >= n_edges) return;

    int s = src_idx[e];
    int t = dst_idx[e];

    // adjacent lanes (h=0,1) hit the SAME 64B line of x -> coalescer merges:
    // one line-transaction per node-gather instead of two.
    float4 xs = x4[(size_t)s * 2 + h];
    float4 xd = x4[(size_t)t * 2 + h];
    float4 a  = ea4[(size_t)e * 2 + h];

    float4 d;
    d.x = (xd.x - xs.x) / a.x;
    d.y = (xd.y - xs.y) / a.y;
    d.z = (xd.z - xs.z) / a.z;
    d.w = (xd.w - xs.w) / a.w;

    out_edge4[(size_t)e * 2 + h] = d;
}

// =============== K2: streaming counting-sort into coarse regions ===============

__global__ __launch_bounds__(APT) void edge_sortk_kernel(
    const int* __restrict__ dst_idx,
    const float4* __restrict__ edge4,
    unsigned* __restrict__ gcur,          // [nc]
    uint4* __restrict__ vals,             // [nc*cap]
    unsigned short* __restrict__ locs,    // [nc*cap]
    int n_edges, int nc, int cap)
{
    __shared__ uint4 pay[EPB];            // 49152 B — bf16 payload (sorted order)
    __shared__ unsigned meta[EPB];        // 12288 B — node id (sorted order)
    __shared__ unsigned hist[NCMAX];
    __shared__ unsigned incl[NCMAX];
    __shared__ unsigned starts[NCMAX];
    __shared__ unsigned cur[NCMAX];
    __shared__ unsigned base[NCMAX];
    __shared__ unsigned wsum[NCMAX / 64], woff[NCMAX / 64];

    for (int c = threadIdx.x; c < NCMAX; c += APT) hist[c] = 0u;
    __syncthreads();

    const int start = blockIdx.x * EPB;
    int lim = n_edges - start;
    if (lim > EPB) lim = EPB;
    if (lim < 0) lim = 0;

    // pass A: histogram of coarse buckets (dst streaming read)
    for (int i = threadIdx.x; i < lim; i += APT) {
        unsigned t = (unsigned)dst_idx[start + i];
        atomicAdd(&hist[t >> NPCSH], 1u);
    }
    __syncthreads();

    scan_bins<NCMAX>(hist, incl, starts, cur, wsum, woff);

    // reserve global run space
    if (threadIdx.x < (unsigned)nc)
        base[threadIdx.x] = hist[threadIdx.x]
            ? atomicAdd(&gcur[threadIdx.x], hist[threadIdx.x]) : 0u;

    // pass B: stream edge_deriv (coalesced), convert bf16, direct-scatter into
    // sorted LDS position
    for (int i = threadIdx.x; i < lim; i += APT) {
        int e = start + i;
        unsigned t = (unsigned)dst_idx[e];      // L2-hot re-read
        float4 d0 = edge4[(size_t)e * 2 + 0];
        float4 d1 = edge4[(size_t)e * 2 + 1];
        unsigned p = atomicAdd(&cur[t >> NPCSH], 1u);
        uint4 v = { pk_bf16(d0.x, d0.y), pk_bf16(d0.z, d0.w),
                    pk_bf16(d1.x, d1.y), pk_bf16(d1.z, d1.w) };
        pay[p] = v;
        meta[p] = t;
    }
    __syncthreads();

    // pass C: coalesced LDS read -> coalesced global run write
    for (int p = threadIdx.x; p < lim; p += APT) {
        unsigned t = meta[p];
        unsigned c = t >> NPCSH;
        unsigned addr = base[c] + ((unsigned)p - starts[c]);
        if (addr < (unsigned)cap) {
            size_t gi = (size_t)c * cap + addr;
            vals[gi] = pay[p];
            locs[gi] = (unsigned short)(t & (NPC - 1));
        }
    }
}

// =============== K3: coarse reduce (round-8, proven ~7 µs) ===============

__global__ __launch_bounds__(BPT) void coarse_reduce_kernel(
    const unsigned* __restrict__ gcur,
    const uint4* __restrict__ vals,
    const unsigned short* __restrict__ locs,
    float4* __restrict__ out_node4,
    int n_nodes, int cap)
{
    __shared__ float acc[NPC * 9];        // 18432 B
    __shared__ uint4 vstage[BCH];         // 24576 B
    __shared__ unsigned hist[NPC];
    __shared__ unsigned incl[NPC];
    __shared__ unsigned starts[NPC];
    __shared__ unsigned cur[NPC];
    __shared__ unsigned wsum[NPC / 64], woff[NPC / 64];

    const int c = blockIdx.x;
    int count = (int)gcur[c];
    if (count > cap) count = cap;
    const uint4* vsrc = vals + (size_t)c * cap;
    const unsigned short* lsrc = locs + (size_t)c * cap;

    for (int j = threadIdx.x; j < NPC * 9; j += BPT) acc[j] = 0.0f;
    __syncthreads();

    for (int cb = 0; cb < count; cb += BCH) {
        int cnt = count - cb;
        if (cnt > BCH) cnt = BCH;

        for (int j = threadIdx.x; j < NPC; j += BPT) hist[j] = 0u;
        __syncthreads();

        uint4 r0, r1;
        unsigned l0 = 0xFFFFu, l1 = 0xFFFFu;
        int i0 = threadIdx.x, i1 = threadIdx.x + BPT;
        if (i0 < cnt) { r0 = vsrc[cb + i0]; l0 = lsrc[cb + i0]; atomicAdd(&hist[l0], 1u); }
        if (i1 < cnt) { r1 = vsrc[cb + i1]; l1 = lsrc[cb + i1]; atomicAdd(&hist[l1], 1u); }
        __syncthreads();

        scan_bins<NPC>(hist, incl, starts, cur, wsum, woff);

        if (l0 != 0xFFFFu) { unsigned p = atomicAdd(&cur[l0], 1u); vstage[p] = r0; }
        if (l1 != 0xFFFFu) { unsigned p = atomicAdd(&cur[l1], 1u); vstage[p] = r1; }
        __syncthreads();

        if (threadIdx.x < NPC) {
            unsigned s = starts[threadIdx.x];
            unsigned e = (threadIdx.x == NPC - 1) ? (unsigned)cnt
                                                  : starts[threadIdx.x + 1];
            if (e > s) {
                float f0 = 0.f, f1 = 0.f, f2 = 0.f, f3 = 0.f;
                float f4 = 0.f, f5 = 0.f, f6 = 0.f, f7 = 0.f;
                for (unsigned j = s; j < e; ++j) {
                    uint4 v = vstage[j];
                    f0 += bf_lo(v.x); f1 += bf_hi(v.x);
                    f2 += bf_lo(v.y); f3 += bf_hi(v.y);
                    f4 += bf_lo(v.z); f5 += bf_hi(v.z);
                    f6 += bf_lo(v.w); f7 += bf_hi(v.w);
                }
                float* a = acc + threadIdx.x * 9;
                a[0] += f0; a[1] += f1; a[2] += f2; a[3] += f3;
                a[4] += f4; a[5] += f5; a[6] += f6; a[7] += f7;
                a[8] += (float)(e - s);
            }
        }
        __syncthreads();
    }

    if (threadIdx.x < NPC) {
        int node = (c << NPCSH) + threadIdx.x;
        if (node < n_nodes) {
            const float* a = acc + threadIdx.x * 9;
            float inv = 1.0f / fmaxf(a[8], 1.0f);
            float4 o0 = { a[0] * inv, a[1] * inv, a[2] * inv, a[3] * inv };
            float4 o1 = { a[4] * inv, a[5] * inv, a[6] * inv, a[7] * inv };
            out_node4[(size_t)node * 2 + 0] = o0;
            out_node4[(size_t)node * 2 + 1] = o1;
        }
    }
}

// =============== pairs path (round-5, proven fallback) ===============

__global__ __launch_bounds__(APT) void edge_phase_kernel(
    const float4* __restrict__ x4,
    const int* __restrict__ src_idx,
    const int* __restrict__ dst_idx,
    const float4* __restrict__ ea4,
    float4* __restrict__ out_edge4,
    unsigned* __restrict__ cursors,
    unsigned* __restrict__ pairs,
    int n_edges, int nb, int cap)
{
    __shared__ unsigned hist[NBMAX];
    __shared__ unsigned base[NBMAX];
    __shared__ unsigned cur[NBMAX];
    __shared__ unsigned tld[EPBF];

    for (int b = threadIdx.x; b < nb; b += APT) { hist[b] = 0u; cur[b] = 0u; }
    __syncthreads();

    const int start = blockIdx.x * EPBF;
    int lim = n_edges - start;
    if (lim > EPBF) lim = EPBF;
    if (lim < 0) lim = 0;

    for (int i = threadIdx.x; i < lim; i += APT) {
        int e = start + i;
        int s = src_idx[e];
        int t = dst_idx[e];
        tld[i] = (unsigned)t;
        float4 xs0 = x4[(size_t)s * 2 + 0];
        float4 xs1 = x4[(size_t)s * 2 + 1];
        float4 xd0 = x4[(size_t)t * 2 + 0];
        float4 xd1 = x4[(size_t)t * 2 + 1];
        float4 a0  = ea4[(size_t)e * 2 + 0];
        float4 a1  = ea4[(size_t)e * 2 + 1];
        float4 d0, d1;
        d0.x = (xd0.x - xs0.x) / a0.x;
        d0.y = (xd0.y - xs0.y) / a0.y;
        d0.z = (xd0.z - xs0.z) / a0.z;
        d0.w = (xd0.w - xs0.w) / a0.w;
        d1.x = (xd1.x - xs1.x) / a1.x;
        d1.y = (xd1.y - xs1.y) / a1.y;
        d1.z = (xd1.z - xs1.z) / a1.z;
        d1.w = (xd1.w - xs1.w) / a1.w;
        out_edge4[(size_t)e * 2 + 0] = d0;
        out_edge4[(size_t)e * 2 + 1] = d1;
        atomicAdd(&hist[t >> BSH], 1u);
    }
    __syncthreads();

    for (int b = threadIdx.x; b < nb; b += APT)
        base[b] = hist[b] ? atomicAdd(&cursors[b], hist[b]) : 0u;
    __syncthreads();

    for (int i = threadIdx.x; i < lim; i += APT) {
        int e = start + i;
        unsigned t = tld[i];
        unsigned b = t >> BSH;
        unsigned p = base[b] + atomicAdd(&cur[b], 1u);
        if (p < (unsigned)cap)
            pairs[(size_t)b * cap + p] = ((unsigned)e << BSH) | (t & BMASK);
    }
}

__device__ __forceinline__ void acc9(float* __restrict__ acc, unsigned loc,
                                     float4 d0, float4 d1) {
    float* a = acc + loc * 9;
    atomicAdd(a + 0, d0.x);
    atomicAdd(a + 1, d0.y);
    atomicAdd(a + 2, d0.z);
    atomicAdd(a + 3, d0.w);
    atomicAdd(a + 4, d1.x);
    atomicAdd(a + 5, d1.y);
    atomicAdd(a + 6, d1.z);
    atomicAdd(a + 7, d1.w);
    atomicAdd(a + 8, 1.0f);
}

__global__ __launch_bounds__(RPT5) void bucket_reduce_kernel(
    const unsigned* __restrict__ cursors,
    const unsigned* __restrict__ pairs,
    const float4* __restrict__ edge4,
    float4* __restrict__ out_node4,
    int n_nodes, int cap)
{
    __shared__ float acc[64 * 9];
    for (int j = threadIdx.x; j < 64 * 9; j += RPT5) acc[j] = 0.0f;
    __syncthreads();

    const int b = blockIdx.x;
    int count = (int)cursors[b];
    if (count > cap) count = cap;
    const unsigned* pb = pairs + (size_t)b * cap;

    for (int i = threadIdx.x; i < count; i += RPT5) {
        unsigned pr = pb[i];
        float4 d0 = edge4[(size_t)(pr >> BSH) * 2 + 0];
        float4 d1 = edge4[(size_t)(pr >> BSH) * 2 + 1];
        acc9(acc, pr & BMASK, d0, d1);
    }
    __syncthreads();

    if (threadIdx.x < 128) {
        int loc  = threadIdx.x >> 1;
        int half = threadIdx.x & 1;
        int node = (b << BSH) + loc;
        if (node < n_nodes) {
            const float* a = acc + loc * 9;
            float inv = 1.0f / fmaxf(a[8], 1.0f);
            float4 o = { a[half * 4 + 0] * inv, a[half * 4 + 1] * inv,
                         a[half * 4 + 2] * inv, a[half * 4 + 3] * inv };
            out_node4[(size_t)node * 2 + half] = o;
        }
    }
}

// =============== atomic fallback (round-2, proven) ===============

__global__ void fb_zero_kernel(float* __restrict__ node_out, int n_node_f,
                               float* __restrict__ counts, int n_counts) {
    int stride = gridDim.x * blockDim.x;
    int tid = blockIdx.x * blockDim.x + threadIdx.x;
    for (int i = tid; i < n_node_f; i += stride) node_out[i] = 0.0f;
    for (int i = tid; i < n_counts; i += stride) counts[i] = 0.0f;
}

__global__ void fb_edge_kernel(const float4* __restrict__ x4,
                               const int* __restrict__ src_idx,
                               const int* __restrict__ dst_idx,
                               const float4* __restrict__ ea4,
                               float4* __restrict__ out_edge4,
                               float* __restrict__ node_sums,
                               float* __restrict__ counts,
                               int n_edges) {
    int e = blockIdx.x * blockDim.x + threadIdx.x;
    if (e >= n_edges) return;
    int s = src_idx[e];
    int t = dst_idx[e];
    float4 xs0 = x4[(size_t)s * 2 + 0];
    float4 xs1 = x4[(size_t)s * 2 + 1];
    float4 xd0 = x4[(size_t)t * 2 + 0];
    float4 xd1 = x4[(size_t)t * 2 + 1];
    float4 a0  = ea4[(size_t)e * 2 + 0];
    float4 a1  = ea4[(size_t)e * 2 + 1];
    float4 d0, d1;
    d0.x = (xd0.x - xs0.x) / a0.x;
    d0.y = (xd0.y - xs0.y) / a0.y;
    d0.z = (xd0.z - xs0.z) / a0.z;
    d0.w = (xd0.w - xs0.w) / a0.w;
    d1.x = (xd1.x - xs1.x) / a1.x;
    d1.y = (xd1.y - xs1.y) / a1.y;
    d1.z = (xd1.z - xs1.z) / a1.z;
    d1.w = (xd1.w - xs1.w) / a1.w;
    out_edge4[(size_t)e * 2 + 0] = d0;
    out_edge4[(size_t)e * 2 + 1] = d1;
    float* sp = node_sums + (size_t)t * D;
    atomicAdd(sp + 0, d0.x);
    atomicAdd(sp + 1, d0.y);
    atomicAdd(sp + 2, d0.z);
    atomicAdd(sp + 3, d0.w);
    atomicAdd(sp + 4, d1.x);
    atomicAdd(sp + 5, d1.y);
    atomicAdd(sp + 6, d1.z);
    atomicAdd(sp + 7, d1.w);
    atomicAdd(counts + t, 1.0f);
}

__global__ void fb_node_kernel(float4* __restrict__ node4,
                               const float* __restrict__ counts,
                               int n_nodes) {
    int n = blockIdx.x * blockDim.x + threadIdx.x;
    if (n >= n_nodes) return;
    float inv = 1.0f / fmaxf(counts[n], 1.0f);
    float4 s0 = node4[(size_t)n * 2 + 0];
    float4 s1 = node4[(size_t)n * 2 + 1];
    s0.x *= inv; s0.y *= inv; s0.z *= inv; s0.w *= inv;
    s1.x *= inv; s1.y *= inv; s1.z *= inv; s1.w *= inv;
    node4[(size_t)n * 2 + 0] = s0;
    node4[(size_t)n * 2 + 1] = s1;
}

// ---------------- launch ----------------

extern "C" void kernel_launch(void* const* d_in, const int* in_sizes, int n_in,
                              void* d_out, int out_size, void* d_ws, size_t ws_size,
                              hipStream_t stream) {
    const float* x  = (const float*)d_in[0];
    const int*   ei = (const int*)d_in[1];
    const float* ea = (const float*)d_in[2];

    const int n_nodes = in_sizes[0] / D;
    const int n_edges = in_sizes[2] / D;

    const int* src_idx = ei;
    const int* dst_idx = ei + n_edges;

    float* out_node = (float*)d_out;
    float* out_edge = out_node + (size_t)n_nodes * D;

    // --- split coarse-sort fast path ---
    {
        const int nc = (n_nodes + NPC - 1) >> NPCSH;
        long long meanc = nc > 0 ? (long long)n_edges / nc : 0;
        int capc = (int)(meanc + meanc / 8 + 1024);
        size_t gcur_b = ((size_t)nc * 4 + 255) & ~(size_t)255;
        size_t vals_b = (size_t)nc * capc * 16;
        size_t locs_b = (size_t)nc * capc * 2;
        size_t need = gcur_b + vals_b + locs_b + 256;

        if (nc >= 1 && nc <= NCMAX && ws_size >= need) {
            unsigned*       gcur = (unsigned*)d_ws;
            uint4*          vals = (uint4*)((char*)d_ws + gcur_b);
            unsigned short* locs = (unsigned short*)((char*)d_ws + gcur_b + vals_b);

            zero_cursors_kernel<<<(nc + 255) / 256, 256, 0, stream>>>(gcur, nc);
            // 2 lanes per edge -> 128 edges per 256-thread block
            edge_compute2_kernel<<<(2 * n_edges + 255) / 256, 256, 0, stream>>>(
                (const float4*)x, src_idx, dst_idx, (const float4*)ea,
                (float4*)out_edge, n_edges);
            int blocksS = (n_edges + EPB - 1) / EPB;
            edge_sortk_kernel<<<blocksS, APT, 0, stream>>>(
                dst_idx, (const float4*)out_edge, gcur, vals, locs,
                n_edges, nc, capc);
            coarse_reduce_kernel<<<nc, BPT, 0, stream>>>(
                gcur, vals, locs, (float4*)out_node, n_nodes, capc);
            return;
        }
    }

    // --- pairs path (round-5) ---
    {
        const int nb = (n_nodes + BMASK) >> BSH;
        int cap = (int)(((long long)n_edges / (nb > 0 ? nb : 1) + 256) * 3 / 2);
        cap = (cap + 3) & ~3;
        size_t cursors_bytes = ((size_t)nb * 4 + 255) & ~(size_t)255;
        size_t need = cursors_bytes + (size_t)nb * cap * 4;
        if (nb <= NBMAX && ws_size >= need) {
            unsigned* cursors = (unsigned*)d_ws;
            unsigned* pairs   = (unsigned*)((char*)d_ws + cursors_bytes);

            int blocksA = (n_edges + EPBF - 1) / EPBF;
            zero_cursors_kernel<<<(nb + 255) / 256, 256, 0, stream>>>(cursors, nb);
            edge_phase_kernel<<<blocksA, APT, 0, stream>>>(
                (const float4*)x, src_idx, dst_idx, (const float4*)ea,
                (float4*)out_edge, cursors, pairs, n_edges, nb, cap);
            bucket_reduce_kernel<<<nb, RPT5, 0, stream>>>(
                cursors, pairs, (const float4*)out_edge, (float4*)out_node,
                n_nodes, cap);
            return;
        }
    }

    // --- atomic fallback ---
    {
        float* counts = (float*)d_ws;
        int n = n_nodes * D;
        int blocks = (n + 255) / 256;
        if (blocks > 2048) blocks = 2048;
        fb_zero_kernel<<<blocks, 256, 0, stream>>>(out_node, n, counts, n_nodes);
        fb_edge_kernel<<<(n_edges + 255) / 256, 256, 0, stream>>>(
            (const float4*)x, src_idx, dst_idx, (const float4*)ea,
            (float4*)out_edge, out_node, counts, n_edges);
        fb_node_kernel<<<(n_nodes + 255) / 256, 256, 0, stream>>>(
            (float4*)out_node, counts, n_nodes);
    }
}